// Round 9
// baseline (227.030 us; speedup 1.0000x reference)
//
#include <hip/hip_runtime.h>
#include <hip/hip_fp16.h>

#define NC_MEM 64
#define NC_IMG 64
#define NC     128
#define B_     32
#define H_     64
#define W_     96
#define HW_    (H_ * W_)      // 6144
#define P_TILE 128            // px per tile
#define T_BLK  3              // tiles per block; grid.x = 48/3 = 16 -> 512 blocks = 2/CU exactly
#define FS     520            // frag stride in ushorts: 512 + 8 pad
#define FOFF(pt, ks) ((((pt) * 4) + (ks)) * FS)
// rotated block placement, applied on every write and read (pure relabeling)
#define XOFF(pt, ks, blk) (FOFF(pt, ks) + ((((blk) + (pt)) & 63) << 3))

// d_ws byte layout
#define WA_HI  0                       // ushort[3][8][4][64][8] (f16 hi, A-frag order)
#define WA_LO  98304                   // f16 lo (w - f16(w))
#define XF_OFF 196608                  // float[32][16]
#define UM_OFF 198656                  // float[32]

typedef _Float16 f16x8 __attribute__((ext_vector_type(8)));
typedef __attribute__((ext_vector_type(4))) float f32x4;

__device__ inline unsigned pk2h(float a, float b) {
    __half2 h = __floats2half2_rn(a, b);
    return *(const unsigned*)&h;
}

// LDS-only barrier (orders ds ops without draining vmcnt); proven safe in v6.
// Essential here: producer global loads issued in seg B stay in flight across
// the barriers until consumed in seg D.
__device__ inline void bar_lds() {
    __builtin_amdgcn_sched_barrier(0);
    asm volatile("s_waitcnt lgkmcnt(0)" ::: "memory");
    __builtin_amdgcn_s_barrier();
    asm volatile("" ::: "memory");
    __builtin_amdgcn_sched_barrier(0);
}

// ---------------------------------------------------------------------------
// prep: blocks 0..191 split W into f16 hi/lo in MFMA A-fragment order;
// block 192 computes xf via adjugate inverse + decodes use_memory.
// ---------------------------------------------------------------------------
__global__ void prep(const float* __restrict__ Ws,
                     const float* __restrict__ prev_ext,
                     const float* __restrict__ cur_ext,
                     const int* __restrict__ mem_idx,
                     const unsigned char* __restrict__ um_raw,
                     unsigned char* __restrict__ wsb) {
    if (blockIdx.x < 192) {
        int idx = blockIdx.x * 256 + threadIdx.x;   // < 49152 = 3*128*128
        int l = idx >> 14, r = idx & 16383, o = r >> 7, c = r & 127;
        float w = Ws[idx];
        __half hi = __float2half_rn(w);
        __half lo = __float2half_rn(w - __half2float(hi));
        int mt = o >> 4, lm = o & 15, ks = c >> 5, kr = c & 31, q = kr >> 3, j = kr & 7;
        int lane = q * 16 + lm;
        int di = ((((l * 8 + mt) * 4 + ks) * 64 + lane) << 3) + j;
        ((unsigned short*)(wsb + WA_HI))[di] = __half_as_ushort(hi);
        ((unsigned short*)(wsb + WA_LO))[di] = __half_as_ushort(lo);
        return;
    }
    int tb = threadIdx.x;
    if (tb >= 64) return;
    bool flag = (tb < 32) && (tb & 3) && (um_raw[tb] != 0);
    bool is_bool = __any(flag);
    if (tb >= B_) return;
    int b = tb;
    bool um = is_bool ? (um_raw[b] != 0) : (((const int*)um_raw)[b] != 0);
    int mi = mem_idx[b];

    float a[16];
#pragma unroll
    for (int i = 0; i < 16; ++i)
        a[i] = um ? prev_ext[mi * 16 + i] : ((i % 5 == 0) ? 1.f : 0.f);

    float s0 = a[0]*a[5]  - a[1]*a[4];
    float s1 = a[0]*a[6]  - a[2]*a[4];
    float s2 = a[0]*a[7]  - a[3]*a[4];
    float s3 = a[1]*a[6]  - a[2]*a[5];
    float s4 = a[1]*a[7]  - a[3]*a[5];
    float s5 = a[2]*a[7]  - a[3]*a[6];
    float c5 = a[10]*a[15] - a[11]*a[14];
    float c4 = a[9]*a[15]  - a[11]*a[13];
    float c3 = a[9]*a[14]  - a[10]*a[13];
    float c2 = a[8]*a[15]  - a[11]*a[12];
    float c1 = a[8]*a[14]  - a[10]*a[12];
    float c0 = a[8]*a[13]  - a[9]*a[12];
    float det = s0*c5 - s1*c4 + s2*c3 + s3*c2 - s4*c1 + s5*c0;
    float id = 1.0f / det;

    float inv[16];
    inv[0]  = ( a[5]*c5  - a[6]*c4  + a[7]*c3)  * id;
    inv[1]  = (-a[1]*c5  + a[2]*c4  - a[3]*c3)  * id;
    inv[2]  = ( a[13]*s5 - a[14]*s4 + a[15]*s3) * id;
    inv[3]  = (-a[9]*s5  + a[10]*s4 - a[11]*s3) * id;
    inv[4]  = (-a[4]*c5  + a[6]*c2  - a[7]*c1)  * id;
    inv[5]  = ( a[0]*c5  - a[2]*c2  + a[3]*c1)  * id;
    inv[6]  = (-a[12]*s5 + a[14]*s2 - a[15]*s1) * id;
    inv[7]  = ( a[8]*s5  - a[10]*s2 + a[11]*s1) * id;
    inv[8]  = ( a[4]*c4  - a[5]*c2  + a[7]*c0)  * id;
    inv[9]  = (-a[0]*c4  + a[1]*c2  - a[3]*c0)  * id;
    inv[10] = ( a[12]*s4 - a[13]*s2 + a[15]*s0) * id;
    inv[11] = (-a[8]*s4  + a[9]*s2  - a[11]*s0) * id;
    inv[12] = (-a[4]*c3  + a[5]*c1  - a[6]*c0)  * id;
    inv[13] = ( a[0]*c3  - a[1]*c1  + a[2]*c0)  * id;
    inv[14] = (-a[12]*s3 + a[13]*s1 - a[14]*s0) * id;
    inv[15] = ( a[8]*s3  - a[9]*s1  + a[10]*s0) * id;

    float* xf = (float*)(wsb + XF_OFF) + b * 16;
#pragma unroll
    for (int i = 0; i < 4; ++i)
#pragma unroll
        for (int j2 = 0; j2 < 4; ++j2) {
            float s = 0.f;
#pragma unroll
            for (int k = 0; k < 4; ++k)
                s += cur_ext[b * 16 + i * 4 + k] * inv[k * 4 + j2];
            xf[i * 4 + j2] = s;
        }
    ((float*)(wsb + UM_OFF))[b] = um ? 1.f : 0.f;
}

// ---------------------------------------------------------------------------
// fused_main v9: WAVE SPECIALIZATION. Evidence through v8: five structurally
// different kernels all 50-53 us; pipe floors MFMA 15.5 + LDS 17 + HBM 14 +
// VALU 10 us/CU sum to the observed time -> phases run serially because
// barrier-lockstep puts every wave in the same phase on the same pipe.
// Fix: waves 0-3 = consumers (MFMA + LDS reads only), waves 4-7 = producers
// (global loads + FTL + pack + LDS writes only). Block owns T_BLK=3 tiles;
// producers prepare tile t+1 into the other LDS buffer while consumers
// compute tile t. Producer loads fly across bar_lds (no vmcnt drain - v6).
// Each role is its own branch with a MATCHING barrier sequence (1+5*3 each),
// so producer staging regs are never statically co-live with consumer acc
// (the liveness overlap is what spilled v5). 1 consumer + 1 producer wave
// per SIMD (round-robin) = the m114 MFMA||VALU co-schedule.
// All staging/fragment/writeback formulas verbatim from v6/v8 -> absmax must
// stay exactly 0.015625.
// ---------------------------------------------------------------------------
__global__ __launch_bounds__(512, 4)
void fused_main(const float* __restrict__ img, const float* __restrict__ mem,
                const int* __restrict__ mem_idx, const float* __restrict__ bs,
                const unsigned char* __restrict__ wsb, float* __restrict__ out) {
    __shared__ unsigned short xh[2][32 * FS]; // 2 x 33280 B -> 2 blocks/CU

    const int t    = threadIdx.x;
    const int b    = blockIdx.y;
    const int hw00 = blockIdx.x * (P_TILE * T_BLK);
    const bool umb = ((const float*)(wsb + UM_OFF))[b] != 0.f;
    const int mi   = mem_idx[b];

    const f16x8* __restrict__ WH = (const f16x8*)(wsb + WA_HI);
    const f16x8* __restrict__ WL = (const f16x8*)(wsb + WA_LO);

    const int lane = t & 63;
    const int wq   = lane >> 4;
    const int lm   = lane & 15;

    // consumer params (waves 0..3)
    const int cw   = (t >> 6) & 3;
    const int mt0  = 2 * cw;        // mt pair 0,2,4,6
    const int mt2  = 4 + cw;        // L2 mt 4..7
    // producer params (waves 4..7 -> tp = t-256 in 0..255)
    const int tp   = t & 255;
    const int q    = tp & 31;       // px quad 0..31 (128 px)
    const int og2  = tp >> 5;       // 0..7; passes cover og2 and og2+8
    const int pt   = q >> 2;        // 0..7

#define FI(l, mt, ks) (((((l) * 8 + (mt)) * 4) + (ks)) * 64 + lane)

    // ---- producer helpers (v6 formulas: og 0..15 x q 0..31) ----
    auto stage_load = [&](int hw0t, int og, f32x4* v) {
        const int px0 = hw0t + q * 4;
        if (umb) {
            const int c0 = og * 8;
            const float* basep = (c0 < NC_MEM)
                ? (mem + ((size_t)mi * NC_MEM + c0) * HW_ + px0)
                : (img + ((size_t)b * NC_IMG + (c0 - NC_MEM)) * HW_ + px0);
#pragma unroll
            for (int cc = 0; cc < 8; ++cc)
                v[cc] = *(const f32x4*)(basep + (size_t)cc * HW_);
        } else {
            const int c0 = og * 4;  // img channel 0..60 (gg = 16+og)
#pragma unroll
            for (int cc = 0; cc < 4; ++cc)
                v[cc] = *(const f32x4*)(img + ((size_t)b * NC_IMG + c0 + cc) * HW_ + px0);
        }
    };
    auto stage_write = [&](unsigned short* xb, int og, f32x4* v, const float* xfv) {
        if (umb) {
            if (og < 4) {              // FTL on channel groups 0..7 (c < 32)
#pragma unroll
                for (int sg = 0; sg < 2; ++sg) {
#pragma unroll
                    for (int i = 0; i < 4; ++i) {
                        float a0 = v[4*sg+0][i], a1 = v[4*sg+1][i];
                        float a2 = v[4*sg+2][i], a3 = v[4*sg+3][i];
                        v[4*sg+0][i] = xfv[0]*a0  + xfv[1]*a1  + xfv[2]*a2  + xfv[3]*a3;
                        v[4*sg+1][i] = xfv[4]*a0  + xfv[5]*a1  + xfv[6]*a2  + xfv[7]*a3;
                        v[4*sg+2][i] = xfv[8]*a0  + xfv[9]*a1  + xfv[10]*a2 + xfv[11]*a3;
                        v[4*sg+3][i] = xfv[12]*a0 + xfv[13]*a1 + xfv[14]*a2 + xfv[15]*a3;
                    }
                }
            }
            const int bk0 = (og & 3) * 16 + (q & 3) * 4;
#pragma unroll
            for (int i = 0; i < 4; ++i) {
                uint4 pk;
                pk.x = pk2h(v[0][i], v[1][i]);
                pk.y = pk2h(v[2][i], v[3][i]);
                pk.z = pk2h(v[4][i], v[5][i]);
                pk.w = pk2h(v[6][i], v[7][i]);
                *(uint4*)&xb[XOFF(pt, og >> 2, bk0 + i)] = pk;
            }
        } else {
            const int gg = 16 + og;
            const int bk0 = ((gg & 7) >> 1) * 16 + (q & 3) * 4;
            const int hoff = (gg & 1) * 4;
#pragma unroll
            for (int i = 0; i < 4; ++i)
                *(uint2*)&xb[XOFF(pt, gg >> 3, bk0 + i) + hoff] =
                    make_uint2(pk2h(v[0][i], v[1][i]), pk2h(v[2][i], v[3][i]));
        }
    };

    if (t < 256) {
        // =================== CONSUMER waves 0..3 ===================
        // B-fragment base offsets (ushort units), valid for both buffers
        int bo[8];
#pragma unroll
        for (int nt = 0; nt < 8; ++nt)
            bo[nt] = XOFF(nt, 0, lane);

        // persistent L0 A-frags (tile-independent!)
        const int kpa = umb ? 0 : 2, kpb = umb ? 1 : 3;
        f16x8 p0h = WH[FI(0, mt0,     kpa)], p0l = WL[FI(0, mt0,     kpa)];
        f16x8 p1h = WH[FI(0, mt0 + 1, kpa)], p1l = WL[FI(0, mt0 + 1, kpa)];
        f16x8 p2h = WH[FI(0, mt0,     kpb)], p2l = WL[FI(0, mt0,     kpb)];
        f16x8 p3h = WH[FI(0, mt0 + 1, kpb)], p3l = WL[FI(0, mt0 + 1, kpb)];

        bar_lds();   // P1: tile0 staged (by producers)

        f32x4 acc[2][8];
        auto runk8 = [&](const unsigned short* xc, int ks,
                         f16x8 ah0, f16x8 al0, f16x8 ah1, f16x8 al1) {
#pragma unroll
            for (int nt = 0; nt < 8; ++nt) {
                f16x8 bh = *(const f16x8*)&xc[bo[nt] + ks * FS];
                acc[0][nt] = __builtin_amdgcn_mfma_f32_16x16x32_f16(ah0, bh, acc[0][nt], 0, 0, 0);
                acc[1][nt] = __builtin_amdgcn_mfma_f32_16x16x32_f16(ah1, bh, acc[1][nt], 0, 0, 0);
                acc[0][nt] = __builtin_amdgcn_mfma_f32_16x16x32_f16(al0, bh, acc[0][nt], 0, 0, 0);
                acc[1][nt] = __builtin_amdgcn_mfma_f32_16x16x32_f16(al1, bh, acc[1][nt], 0, 0, 0);
            }
        };
        auto writeback = [&](unsigned short* xb) {
#pragma unroll
            for (int mi2 = 0; mi2 < 2; ++mi2) {
                const int mt = mt0 + mi2;
                const int ks2 = mt >> 1;
                const int lane_f = ((mt & 1) * 2 + (wq >> 1)) * 16 + lm;
                const int j0 = (wq & 1) * 4;
#pragma unroll
                for (int nt = 0; nt < 8; ++nt) {
                    float v0 = fmaxf(acc[mi2][nt][0], 0.f);
                    float v1 = fmaxf(acc[mi2][nt][1], 0.f);
                    float v2 = fmaxf(acc[mi2][nt][2], 0.f);
                    float v3 = fmaxf(acc[mi2][nt][3], 0.f);
                    *(uint2*)&xb[XOFF(nt, ks2, lane_f) + j0] =
                        make_uint2(pk2h(v0, v1), pk2h(v2, v3));
                }
            }
        };

#pragma unroll
        for (int tt = 0; tt < T_BLK; ++tt) {
            unsigned short* xc = xh[tt & 1];
            const int hw0t = hw00 + tt * P_TILE;

            // ---- seg A: layer 0 ----
#pragma unroll
            for (int mi2 = 0; mi2 < 2; ++mi2) {
                f32x4 bv = *(const f32x4*)&bs[0 * NC + (mt0 + mi2) * 16 + wq * 4];
#pragma unroll
                for (int nt = 0; nt < 8; ++nt) acc[mi2][nt] = bv;
            }
            __builtin_amdgcn_s_setprio(1);
            if (umb) {
                runk8(xc, 0, p0h, p0l, p1h, p1l);
                runk8(xc, 1, p2h, p2l, p3h, p3l);
                runk8(xc, 2, WH[FI(0, mt0, 2)], WL[FI(0, mt0, 2)],
                             WH[FI(0, mt0 + 1, 2)], WL[FI(0, mt0 + 1, 2)]);
                runk8(xc, 3, WH[FI(0, mt0, 3)], WL[FI(0, mt0, 3)],
                             WH[FI(0, mt0 + 1, 3)], WL[FI(0, mt0 + 1, 3)]);
            } else {
                runk8(xc, 2, p0h, p0l, p1h, p1l);
                runk8(xc, 3, p2h, p2l, p3h, p3l);
            }
            __builtin_amdgcn_s_setprio(0);
            bar_lds();              // end A
            // ---- seg B: L0 writeback ----
            writeback(xc);
            bar_lds();              // end B
            // ---- seg C: layer 1 ----
#pragma unroll
            for (int mi2 = 0; mi2 < 2; ++mi2) {
                f32x4 bv = *(const f32x4*)&bs[1 * NC + (mt0 + mi2) * 16 + wq * 4];
#pragma unroll
                for (int nt = 0; nt < 8; ++nt) acc[mi2][nt] = bv;
            }
            __builtin_amdgcn_s_setprio(1);
            runk8(xc, 0, WH[FI(1, mt0, 0)], WL[FI(1, mt0, 0)],
                         WH[FI(1, mt0 + 1, 0)], WL[FI(1, mt0 + 1, 0)]);
            runk8(xc, 1, WH[FI(1, mt0, 1)], WL[FI(1, mt0, 1)],
                         WH[FI(1, mt0 + 1, 1)], WL[FI(1, mt0 + 1, 1)]);
            runk8(xc, 2, WH[FI(1, mt0, 2)], WL[FI(1, mt0, 2)],
                         WH[FI(1, mt0 + 1, 2)], WL[FI(1, mt0 + 1, 2)]);
            runk8(xc, 3, WH[FI(1, mt0, 3)], WL[FI(1, mt0, 3)],
                         WH[FI(1, mt0 + 1, 3)], WL[FI(1, mt0 + 1, 3)]);
            __builtin_amdgcn_s_setprio(0);
            bar_lds();              // end C
            // ---- seg D: L1 writeback ----
            writeback(xc);
            bar_lds();              // end D
            // ---- seg E: layer 2 + store ----
            {
                f32x4 a2[8];
                f32x4 bv = *(const f32x4*)&bs[2 * NC + mt2 * 16 + wq * 4];
#pragma unroll
                for (int nt = 0; nt < 8; ++nt) a2[nt] = bv;
                __builtin_amdgcn_s_setprio(1);
#pragma unroll
                for (int ks = 0; ks < 4; ++ks) {
                    f16x8 ah = WH[FI(2, mt2, ks)], al = WL[FI(2, mt2, ks)];
#pragma unroll
                    for (int nt = 0; nt < 8; ++nt) {
                        f16x8 bh = *(const f16x8*)&xc[bo[nt] + ks * FS];
                        a2[nt] = __builtin_amdgcn_mfma_f32_16x16x32_f16(ah, bh, a2[nt], 0, 0, 0);
                        a2[nt] = __builtin_amdgcn_mfma_f32_16x16x32_f16(al, bh, a2[nt], 0, 0, 0);
                    }
                }
                __builtin_amdgcn_s_setprio(0);
                const int oc0 = mt2 * 16 + wq * 4 - 64; // 0..63
#pragma unroll
                for (int nt = 0; nt < 8; ++nt) {
                    float* dst = out + ((size_t)b * 64 + oc0) * HW_ + hw0t + nt * 16 + lm;
#pragma unroll
                    for (int r = 0; r < 4; ++r)
                        __builtin_nontemporal_store(a2[nt][r], dst + (size_t)r * HW_);
                }
            }
            bar_lds();              // end E (tile end)
        }
    } else {
        // =================== PRODUCER waves 4..7 ===================
        float xfv[16];
        if (umb) {
            const float* xfp = (const float*)(wsb + XF_OFF) + b * 16;
#pragma unroll
            for (int j = 0; j < 4; ++j)
                *(f32x4*)&xfv[j * 4] = *(const f32x4*)&xfp[j * 4];
        }
        // prologue: stage tile 0 into xh[0] (two sequential passes)
        {
            f32x4 v[8];
            stage_load(hw00, og2, v);
            stage_write(xh[0], og2, v, xfv);
            stage_load(hw00, og2 + 8, v);
            stage_write(xh[0], og2 + 8, v, xfv);
        }
        bar_lds();   // P1: tile0 staged

#pragma unroll
        for (int tt = 0; tt < T_BLK; ++tt) {
            unsigned short* xn = xh[(tt + 1) & 1];
            f32x4 v0[8], v1[8];
            // ---- seg A: idle ----
            bar_lds();              // end A
            // ---- seg B: issue next tile's loads (fly across barriers) ----
            if (tt + 1 < T_BLK) {
                stage_load(hw00 + (tt + 1) * P_TILE, og2,     v0);
                stage_load(hw00 + (tt + 1) * P_TILE, og2 + 8, v1);
            }
            bar_lds();              // end B
            // ---- seg C: idle (loads in flight) ----
            bar_lds();              // end C
            // ---- seg D: FTL + pack + write into the free buffer ----
            if (tt + 1 < T_BLK) {
                stage_write(xn, og2,     v0, xfv);
                stage_write(xn, og2 + 8, v1, xfv);
            }
            bar_lds();              // end D
            // ---- seg E: idle ----
            bar_lds();              // end E (tile end)
        }
    }
#undef FI
}

extern "C" void kernel_launch(void* const* d_in, const int* in_sizes, int n_in,
                              void* d_out, int out_size, void* d_ws, size_t ws_size,
                              hipStream_t stream) {
    const float* img  = (const float*)d_in[0];
    const float* mem  = (const float*)d_in[1];
    const float* pext = (const float*)d_in[2];
    const float* cext = (const float*)d_in[3];
    const int*   midx = (const int*)d_in[4];
    const unsigned char* umem = (const unsigned char*)d_in[5];
    const float* Ws   = (const float*)d_in[6];
    const float* bs   = (const float*)d_in[7];
    float* out = (float*)d_out;
    unsigned char* wsb = (unsigned char*)d_ws;

    hipLaunchKernelGGL(prep, dim3(193), dim3(256), 0, stream,
                       Ws, pext, cext, midx, umem, wsb);
    hipLaunchKernelGGL(fused_main, dim3(HW_ / (P_TILE * T_BLK), B_), dim3(512), 0, stream,
                       img, mem, midx, bs, wsb, out);
}

// Round 10
// 161.669 us; speedup vs baseline: 1.4043x; 1.4043x over previous
//
#include <hip/hip_runtime.h>
#include <hip/hip_fp16.h>

#define NC_MEM 64
#define NC_IMG 64
#define NC     128
#define B_     32
#define H_     64
#define W_     96
#define HW_    (H_ * W_)      // 6144
#define P_TILE 64             // 64-px tiles, 256-thread blocks
#define NTILES (HW_ / P_TILE) // 96
#define FS     520            // frag stride in ushorts: 512 + 8 pad
#define FOFF(pt, ks) ((((pt) * 4) + (ks)) * FS)
// rotated block placement, applied on every write and read (pure relabeling)
#define XOFF(pt, ks, blk) (FOFF(pt, ks) + ((((blk) + (pt)) & 63) << 3))

// d_ws byte layout
#define WA_HI  0                       // ushort[3][8][4][64][8] (f16 hi, A-frag order)
#define WA_LO  98304                   // f16 lo (w - f16(w))
#define XF_OFF 196608                  // float[32][16]
#define UM_OFF 198656                  // float[32]

typedef _Float16 f16x8 __attribute__((ext_vector_type(8)));
typedef __attribute__((ext_vector_type(4))) float f32x4;

__device__ inline unsigned pk2h(float a, float b) {
    __half2 h = __floats2half2_rn(a, b);
    return *(const unsigned*)&h;
}

// LDS-only barrier (orders ds ops without draining vmcnt); proven safe in v6.
__device__ inline void bar_lds() {
    __builtin_amdgcn_sched_barrier(0);
    asm volatile("s_waitcnt lgkmcnt(0)" ::: "memory");
    __builtin_amdgcn_s_barrier();
    asm volatile("" ::: "memory");
    __builtin_amdgcn_sched_barrier(0);
}

// ---------------------------------------------------------------------------
// prep v10: COALESCED W-split. Old prep assigned one SOURCE element per
// thread -> two 2-byte SCATTER stores (A-frag permutation), ~12% store
// efficiency over 196 KB, serial before fused_main (the only prior prep fix,
// v1->v2 ballot, was worth -9 us on dur_us -> prep is on the critical path).
// New: one thread per 8 consecutive DEST ushorts (tid = di>>3). Inverse map:
//   lane=tid&63, ks=(tid>>6)&3, mtl=tid>>8, l=mtl>>3, mt=mtl&7,
//   o=mt*16+(lane&15), c=ks*32+(lane>>4)*8+j  (j=0..7)
// -> the 8 sources are 8 CONSECUTIVE floats (two aligned float4 loads; 4
// lanes fully cover each 128B line), and hi/lo writes are 16B contiguous
// per thread (1KB/wave instruction). Identical per-element rounding math.
// Block 24 computes xf via adjugate inverse + decodes use_memory (unchanged).
// ---------------------------------------------------------------------------
__global__ void prep(const float* __restrict__ Ws,
                     const float* __restrict__ prev_ext,
                     const float* __restrict__ cur_ext,
                     const int* __restrict__ mem_idx,
                     const unsigned char* __restrict__ um_raw,
                     unsigned char* __restrict__ wsb) {
    if (blockIdx.x < 24) {
        int tid  = blockIdx.x * 256 + threadIdx.x;  // 0..6143, one per 8 dest ushorts
        int lane = tid & 63;
        int ks   = (tid >> 6) & 3;
        int mtl  = tid >> 8;                        // l*8+mt, 0..23
        int l    = mtl >> 3, mt = mtl & 7;
        int o    = mt * 16 + (lane & 15);
        int c0   = ks * 32 + (lane >> 4) * 8;
        const float* src = Ws + ((size_t)(l * 128 + o) * 128 + c0);
        f32x4 va = *(const f32x4*)src;
        f32x4 vb = *(const f32x4*)(src + 4);
        float v[8] = {va[0], va[1], va[2], va[3], vb[0], vb[1], vb[2], vb[3]};
        unsigned hs[4], ls[4];
#pragma unroll
        for (int p = 0; p < 4; ++p) {
            __half h0 = __float2half_rn(v[2*p]);
            __half h1 = __float2half_rn(v[2*p+1]);
            __half l0 = __float2half_rn(v[2*p]   - __half2float(h0));
            __half l1 = __float2half_rn(v[2*p+1] - __half2float(h1));
            hs[p] = (unsigned)__half_as_ushort(h0) | ((unsigned)__half_as_ushort(h1) << 16);
            ls[p] = (unsigned)__half_as_ushort(l0) | ((unsigned)__half_as_ushort(l1) << 16);
        }
        uint4 ph = make_uint4(hs[0], hs[1], hs[2], hs[3]);
        uint4 pl = make_uint4(ls[0], ls[1], ls[2], ls[3]);
        *(uint4*)&((unsigned short*)(wsb + WA_HI))[(size_t)tid * 8] = ph;
        *(uint4*)&((unsigned short*)(wsb + WA_LO))[(size_t)tid * 8] = pl;
        return;
    }
    int tb = threadIdx.x;
    if (tb >= 64) return;
    bool flag = (tb < 32) && (tb & 3) && (um_raw[tb] != 0);
    bool is_bool = __any(flag);
    if (tb >= B_) return;
    int b = tb;
    bool um = is_bool ? (um_raw[b] != 0) : (((const int*)um_raw)[b] != 0);
    int mi = mem_idx[b];

    float a[16];
#pragma unroll
    for (int i = 0; i < 16; ++i)
        a[i] = um ? prev_ext[mi * 16 + i] : ((i % 5 == 0) ? 1.f : 0.f);

    float s0 = a[0]*a[5]  - a[1]*a[4];
    float s1 = a[0]*a[6]  - a[2]*a[4];
    float s2 = a[0]*a[7]  - a[3]*a[4];
    float s3 = a[1]*a[6]  - a[2]*a[5];
    float s4 = a[1]*a[7]  - a[3]*a[5];
    float s5 = a[2]*a[7]  - a[3]*a[6];
    float c5 = a[10]*a[15] - a[11]*a[14];
    float c4 = a[9]*a[15]  - a[11]*a[13];
    float c3 = a[9]*a[14]  - a[10]*a[13];
    float c2 = a[8]*a[15]  - a[11]*a[12];
    float c1 = a[8]*a[14]  - a[10]*a[12];
    float c0 = a[8]*a[13]  - a[9]*a[12];
    float det = s0*c5 - s1*c4 + s2*c3 + s3*c2 - s4*c1 + s5*c0;
    float id = 1.0f / det;

    float inv[16];
    inv[0]  = ( a[5]*c5  - a[6]*c4  + a[7]*c3)  * id;
    inv[1]  = (-a[1]*c5  + a[2]*c4  - a[3]*c3)  * id;
    inv[2]  = ( a[13]*s5 - a[14]*s4 + a[15]*s3) * id;
    inv[3]  = (-a[9]*s5  + a[10]*s4 - a[11]*s3) * id;
    inv[4]  = (-a[4]*c5  + a[6]*c2  - a[7]*c1)  * id;
    inv[5]  = ( a[0]*c5  - a[2]*c2  + a[3]*c1)  * id;
    inv[6]  = (-a[12]*s5 + a[14]*s2 - a[15]*s1) * id;
    inv[7]  = ( a[8]*s5  - a[10]*s2 + a[11]*s1) * id;
    inv[8]  = ( a[4]*c4  - a[5]*c2  + a[7]*c0)  * id;
    inv[9]  = (-a[0]*c4  + a[1]*c2  - a[3]*c0)  * id;
    inv[10] = ( a[12]*s4 - a[13]*s2 + a[15]*s0) * id;
    inv[11] = (-a[8]*s4  + a[9]*s2  - a[11]*s0) * id;
    inv[12] = (-a[4]*c3  + a[5]*c1  - a[6]*c0)  * id;
    inv[13] = ( a[0]*c3  - a[1]*c1  + a[2]*c0)  * id;
    inv[14] = (-a[12]*s3 + a[13]*s1 - a[14]*s0) * id;
    inv[15] = ( a[8]*s3  - a[9]*s1  + a[10]*s0) * id;

    float* xf = (float*)(wsb + XF_OFF) + b * 16;
#pragma unroll
    for (int i = 0; i < 4; ++i)
#pragma unroll
        for (int j2 = 0; j2 < 4; ++j2) {
            float s = 0.f;
#pragma unroll
            for (int k = 0; k < 4; ++k)
                s += cur_ext[b * 16 + i * 4 + k] * inv[k * 4 + j2];
            xf[i * 4 + j2] = s;
        }
    ((float*)(wsb + UM_OFF))[b] = um ? 1.f : 0.f;
}

// ---------------------------------------------------------------------------
// fused_main: v8 VERBATIM (best measured: 50.5 us dispatch, 160.65 dur_us;
// VGPR 52, no spill, FETCH 36.8 / WRITE 52.3 MB). v9's wave specialization
// spilled (consumer acc[2][8] + producer v[8]x2 both exceed the 64-reg
// natural budget); kept out. This round isolates the prep fix.
// ---------------------------------------------------------------------------
__global__ __launch_bounds__(256, 4)
void fused_main(const float* __restrict__ img, const float* __restrict__ mem,
                const int* __restrict__ mem_idx, const float* __restrict__ bs,
                const unsigned char* __restrict__ wsb, float* __restrict__ out) {
    __shared__ unsigned short xh[16 * FS]; // 16640 B

    const int t   = threadIdx.x;
    const int b   = blockIdx.y;
    const int hw0 = blockIdx.x * P_TILE;
    const bool umb = ((const float*)(wsb + UM_OFF))[b] != 0.f;
    const int mi  = mem_idx[b];

    const f16x8* __restrict__ WH = (const f16x8*)(wsb + WA_HI);
    const f16x8* __restrict__ WL = (const f16x8*)(wsb + WA_LO);

    const int w    = t >> 6;        // 0..3
    const int lane = t & 63;
    const int wq   = lane >> 4;
    const int lm   = lane & 15;
    const int mt0  = 2 * w;         // wave's mt pair: 0,2,4,6
    const int mt2  = 4 + w;         // wave's L2 mt: 4..7

#define FI(l, mt, ks) (((((l) * 8 + (mt)) * 4) + (ks)) * 64 + lane)

    // ---- stage: global f32 -> (FTL) -> f16 in LDS, rotated frag order ----
    {
        const int q   = t & 15;        // px quad: px = 4q..4q+3 (0..63)
        const int og  = t >> 4;        // channel octet 0..15
        const int px0 = hw0 + q * 4;
        const int pt  = q >> 2;        // 0..3
        if (umb) {
            const int c0 = og * 8;     // 8 channels, one side of 64
            const float* basep = (c0 < NC_MEM)
                ? (mem + ((size_t)mi * NC_MEM + c0) * HW_ + px0)
                : (img + ((size_t)b * NC_IMG + (c0 - NC_MEM)) * HW_ + px0);
            f32x4 v[8];
#pragma unroll
            for (int cc = 0; cc < 8; ++cc)
                v[cc] = *(const f32x4*)(basep + (size_t)cc * HW_);
            if (og < 4) {              // FTL on channel groups 0..7 (c < 32)
                float xfv[16];
                const float* xfp = (const float*)(wsb + XF_OFF) + b * 16;
#pragma unroll
                for (int j = 0; j < 4; ++j)
                    *(f32x4*)&xfv[j * 4] = *(const f32x4*)&xfp[j * 4];
#pragma unroll
                for (int sg = 0; sg < 2; ++sg) {
#pragma unroll
                    for (int i = 0; i < 4; ++i) {
                        float a0 = v[4*sg+0][i], a1 = v[4*sg+1][i];
                        float a2 = v[4*sg+2][i], a3 = v[4*sg+3][i];
                        v[4*sg+0][i] = xfv[0]*a0  + xfv[1]*a1  + xfv[2]*a2  + xfv[3]*a3;
                        v[4*sg+1][i] = xfv[4]*a0  + xfv[5]*a1  + xfv[6]*a2  + xfv[7]*a3;
                        v[4*sg+2][i] = xfv[8]*a0  + xfv[9]*a1  + xfv[10]*a2 + xfv[11]*a3;
                        v[4*sg+3][i] = xfv[12]*a0 + xfv[13]*a1 + xfv[14]*a2 + xfv[15]*a3;
                    }
                }
            }
            const int bk0 = (og & 3) * 16 + (q & 3) * 4;
#pragma unroll
            for (int i = 0; i < 4; ++i) {
                uint4 pk;
                pk.x = pk2h(v[0][i], v[1][i]);
                pk.y = pk2h(v[2][i], v[3][i]);
                pk.z = pk2h(v[4][i], v[5][i]);
                pk.w = pk2h(v[6][i], v[7][i]);
                *(uint4*)&xh[XOFF(pt, og >> 2, bk0 + i)] = pk;
            }
        } else {
            // img channels only (groups 16..31); mem rows never read in L0
            const int gg = 16 + og;
            const int c0 = gg * 4 - NC_MEM;  // img channel 0..60
            f32x4 u[4];
#pragma unroll
            for (int cc = 0; cc < 4; ++cc)
                u[cc] = *(const f32x4*)(img + ((size_t)b * NC_IMG + c0 + cc) * HW_ + px0);
            const int bk0 = ((gg & 7) >> 1) * 16 + (q & 3) * 4;
            const int hoff = (gg & 1) * 4;
#pragma unroll
            for (int i = 0; i < 4; ++i)
                *(uint2*)&xh[XOFF(pt, gg >> 3, bk0 + i) + hoff] =
                    make_uint2(pk2h(u[0][i], u[1][i]), pk2h(u[2][i], u[3][i]));
        }
    }

    // ---- B-fragment read pointers: computed once, valid for all layers ----
    const unsigned short* bp[4];
#pragma unroll
    for (int nt = 0; nt < 4; ++nt)
        bp[nt] = &xh[XOFF(nt, 0, lane)];

    // ---- prefetch layer-0 A frags before the barrier ----
    const int kpa = umb ? 0 : 2, kpb = umb ? 1 : 3;
    f16x8 p0h = WH[FI(0, mt0,     kpa)], p0l = WL[FI(0, mt0,     kpa)];
    f16x8 p1h = WH[FI(0, mt0 + 1, kpa)], p1l = WL[FI(0, mt0 + 1, kpa)];
    f16x8 p2h = WH[FI(0, mt0,     kpb)], p2l = WL[FI(0, mt0,     kpb)];
    f16x8 p3h = WH[FI(0, mt0 + 1, kpb)], p3l = WL[FI(0, mt0 + 1, kpb)];

    bar_lds();   // B1: stage complete

    f32x4 acc[2][4];

    auto run_ks = [&](int ks, f16x8 ah0, f16x8 al0, f16x8 ah1, f16x8 al1) {
#pragma unroll
        for (int nt = 0; nt < 4; ++nt) {
            f16x8 bh = *(const f16x8*)(bp[nt] + ks * FS);
            acc[0][nt] = __builtin_amdgcn_mfma_f32_16x16x32_f16(ah0, bh, acc[0][nt], 0, 0, 0);
            acc[1][nt] = __builtin_amdgcn_mfma_f32_16x16x32_f16(ah1, bh, acc[1][nt], 0, 0, 0);
            acc[0][nt] = __builtin_amdgcn_mfma_f32_16x16x32_f16(al0, bh, acc[0][nt], 0, 0, 0);
            acc[1][nt] = __builtin_amdgcn_mfma_f32_16x16x32_f16(al1, bh, acc[1][nt], 0, 0, 0);
        }
    };
    auto writeback = [&]() {
#pragma unroll
        for (int mi2 = 0; mi2 < 2; ++mi2) {
            const int mt = mt0 + mi2;
            const int ks2 = mt >> 1;
            const int lane_f = ((mt & 1) * 2 + (wq >> 1)) * 16 + lm;
            const int j0 = (wq & 1) * 4;
#pragma unroll
            for (int nt = 0; nt < 4; ++nt) {
                float v0 = fmaxf(acc[mi2][nt][0], 0.f);
                float v1 = fmaxf(acc[mi2][nt][1], 0.f);
                float v2 = fmaxf(acc[mi2][nt][2], 0.f);
                float v3 = fmaxf(acc[mi2][nt][3], 0.f);
                *(uint2*)&xh[XOFF(nt, ks2, lane_f) + j0] =
                    make_uint2(pk2h(v0, v1), pk2h(v2, v3));
            }
        }
    };

    // ---------------- layer 0 ----------------
#pragma unroll
    for (int mi2 = 0; mi2 < 2; ++mi2) {
        f32x4 bv = *(const f32x4*)&bs[0 * NC + (mt0 + mi2) * 16 + wq * 4];
#pragma unroll
        for (int nt = 0; nt < 4; ++nt) acc[mi2][nt] = bv;
    }
    __builtin_amdgcn_s_setprio(1);
    if (umb) {
        run_ks(0, p0h, p0l, p1h, p1l);
        run_ks(1, p2h, p2l, p3h, p3l);
        run_ks(2, WH[FI(0, mt0, 2)], WL[FI(0, mt0, 2)],
                  WH[FI(0, mt0 + 1, 2)], WL[FI(0, mt0 + 1, 2)]);
        run_ks(3, WH[FI(0, mt0, 3)], WL[FI(0, mt0, 3)],
                  WH[FI(0, mt0 + 1, 3)], WL[FI(0, mt0 + 1, 3)]);
    } else {
        run_ks(2, p0h, p0l, p1h, p1l);
        run_ks(3, p2h, p2l, p3h, p3l);
    }
    __builtin_amdgcn_s_setprio(0);
    // prefetch layer-1 ks0/ks1 across the barriers
    f16x8 q0h = WH[FI(1, mt0, 0)],     q0l = WL[FI(1, mt0, 0)];
    f16x8 q1h = WH[FI(1, mt0 + 1, 0)], q1l = WL[FI(1, mt0 + 1, 0)];
    f16x8 q2h = WH[FI(1, mt0, 1)],     q2l = WL[FI(1, mt0, 1)];
    f16x8 q3h = WH[FI(1, mt0 + 1, 1)], q3l = WL[FI(1, mt0 + 1, 1)];
    bar_lds();              // B2: all layer-0 reads of xh done
    writeback();            // overwrite xh in place
    bar_lds();              // B3: layer-0 output visible

    // ---------------- layer 1 ----------------
#pragma unroll
    for (int mi2 = 0; mi2 < 2; ++mi2) {
        f32x4 bv = *(const f32x4*)&bs[1 * NC + (mt0 + mi2) * 16 + wq * 4];
#pragma unroll
        for (int nt = 0; nt < 4; ++nt) acc[mi2][nt] = bv;
    }
    __builtin_amdgcn_s_setprio(1);
    run_ks(0, q0h, q0l, q1h, q1l);
    run_ks(1, q2h, q2l, q3h, q3l);
    run_ks(2, WH[FI(1, mt0, 2)], WL[FI(1, mt0, 2)],
              WH[FI(1, mt0 + 1, 2)], WL[FI(1, mt0 + 1, 2)]);
    run_ks(3, WH[FI(1, mt0, 3)], WL[FI(1, mt0, 3)],
              WH[FI(1, mt0 + 1, 3)], WL[FI(1, mt0 + 1, 3)]);
    __builtin_amdgcn_s_setprio(0);
    // prefetch ALL layer-2 A frags (single mt per wave -> 8 frags)
    f16x8 r0h = WH[FI(2, mt2, 0)], r0l = WL[FI(2, mt2, 0)];
    f16x8 r1h = WH[FI(2, mt2, 1)], r1l = WL[FI(2, mt2, 1)];
    f16x8 r2h = WH[FI(2, mt2, 2)], r2l = WL[FI(2, mt2, 2)];
    f16x8 r3h = WH[FI(2, mt2, 3)], r3l = WL[FI(2, mt2, 3)];
    bar_lds();              // B4: all layer-1 reads of xh done
    writeback();
    bar_lds();              // B5: layer-1 output visible

    // ---------------- layer 2: out channels 64..127 only ----------------
    {
        f32x4 a2[4];
        f32x4 bv = *(const f32x4*)&bs[2 * NC + mt2 * 16 + wq * 4];
#pragma unroll
        for (int nt = 0; nt < 4; ++nt) a2[nt] = bv;
        auto run2 = [&](int ks, f16x8 ah, f16x8 al) {
#pragma unroll
            for (int nt = 0; nt < 4; ++nt) {
                f16x8 bh = *(const f16x8*)(bp[nt] + ks * FS);
                a2[nt] = __builtin_amdgcn_mfma_f32_16x16x32_f16(ah, bh, a2[nt], 0, 0, 0);
                a2[nt] = __builtin_amdgcn_mfma_f32_16x16x32_f16(al, bh, a2[nt], 0, 0, 0);
            }
        };
        __builtin_amdgcn_s_setprio(1);
        run2(0, r0h, r0l);
        run2(1, r1h, r1l);
        run2(2, r2h, r2l);
        run2(3, r3h, r3l);
        __builtin_amdgcn_s_setprio(0);
        const int oc0 = mt2 * 16 + wq * 4 - 64; // 0..60
#pragma unroll
        for (int nt = 0; nt < 4; ++nt) {
            float* dst = out + ((size_t)b * 64 + oc0) * HW_ + hw0 + nt * 16 + lm;
#pragma unroll
            for (int r = 0; r < 4; ++r)
                __builtin_nontemporal_store(a2[nt][r], dst + (size_t)r * HW_);
        }
    }
#undef FI
}

extern "C" void kernel_launch(void* const* d_in, const int* in_sizes, int n_in,
                              void* d_out, int out_size, void* d_ws, size_t ws_size,
                              hipStream_t stream) {
    const float* img  = (const float*)d_in[0];
    const float* mem  = (const float*)d_in[1];
    const float* pext = (const float*)d_in[2];
    const float* cext = (const float*)d_in[3];
    const int*   midx = (const int*)d_in[4];
    const unsigned char* umem = (const unsigned char*)d_in[5];
    const float* Ws   = (const float*)d_in[6];
    const float* bs   = (const float*)d_in[7];
    float* out = (float*)d_out;
    unsigned char* wsb = (unsigned char*)d_ws;

    hipLaunchKernelGGL(prep, dim3(25), dim3(256), 0, stream,
                       Ws, pext, cext, midx, umem, wsb);
    hipLaunchKernelGGL(fused_main, dim3(NTILES, B_), dim3(256), 0, stream,
                       img, mem, midx, bs, wsb, out);
}